// Round 2
// baseline (779.799 us; speedup 1.0000x reference)
//
#include <hip/hip_runtime.h>
#include <hip/hip_cooperative_groups.h>
#include <hip/hip_fp16.h>
#include <math.h>

namespace cg = cooperative_groups;

#define WAVE   64
#define NPB    32          // nodes per window (power of 2)
#define BLOCKT 256
#define SMAX   2           // stashed 1024-edge chunks (covers <=2048 edges/window)

// ---- constants from the reference ----
#define KC        2.2281692032865347f   // 7/pi
#define H         0.05f
#define INV_H2    400.0f
#define INV_H3    8000.0f
#define EPS_REF   0.00025f              // h^2 * 0.1
#define K_OUT     0.24261080f           // 2*h*DELTA*C0
#define REST_RHO  1000.0f

__device__ __forceinline__ float wendland_dkdq(float q) {
    float o = 1.f - q;
    return -20.f * q * o * o * o * KC;
}

union H2F { __half2 h; float f; };
__device__ __forceinline__ float   h2_as_f(__half2 h) { H2F u; u.h = h; return u.f; }
__device__ __forceinline__ __half2 f_as_h2(float f)   { H2F u; u.f = f; return u.h; }

// largest li in [0,NPB) with rp[li] <= e   (rp[0] <= e < rp[NPB] guaranteed)
__device__ __forceinline__ int li_search(const int* rp, int e) {
    int lo = 0;
#pragma unroll
    for (int s = NPB / 2; s >= 1; s >>= 1) lo += (rp[lo + s] <= e) ? s : 0;
    return lo;
}

// ---------------------------------------------------------------------------
// 4-edge-per-lane segmented accumulate via LDS float atomics (ds_add_f32).
// Equal keys contiguous; key<0 skipped (-1 groups only at chunk ends).
// No cross-lane scan: zero serial dependency; contention ~degree/4-way.
// All indices static (rule #20).
// ---------------------------------------------------------------------------
template<int NV>
__device__ __forceinline__ void seg_atomic4(const int k[4], float v[4][NV], float* base) {
    const bool s01 = (k[1] == k[0]);
    const bool s12 = (k[2] == k[1]);
    const bool s23 = (k[3] == k[2]);
    if (k[0] >= 0) {
        float s[NV];
#pragma unroll
        for (int c = 0; c < NV; ++c) {
            float t = v[0][c];
            if (s01)               t += v[1][c];
            if (s01 && s12)        t += v[2][c];
            if (s01 && s12 && s23) t += v[3][c];
            s[c] = t;
        }
#pragma unroll
        for (int c = 0; c < NV; ++c) atomicAdd(base + k[0] * NV + c, s[c]);
    }
    if (k[1] >= 0 && !s01) {
        float s[NV];
#pragma unroll
        for (int c = 0; c < NV; ++c) {
            float t = v[1][c];
            if (s12)        t += v[2][c];
            if (s12 && s23) t += v[3][c];
            s[c] = t;
        }
#pragma unroll
        for (int c = 0; c < NV; ++c) atomicAdd(base + k[1] * NV + c, s[c]);
    }
    if (k[2] >= 0 && !s12) {
        float s[NV];
#pragma unroll
        for (int c = 0; c < NV; ++c) {
            float t = v[2][c];
            if (s23) t += v[3][c];
            s[c] = t;
        }
#pragma unroll
        for (int c = 0; c < NV; ++c) atomicAdd(base + k[2] * NV + c, s[c]);
    }
    if (k[3] >= 0 && !s23) {
#pragma unroll
        for (int c = 0; c < NV; ++c) atomicAdd(base + k[3] * NV + c, v[3][c]);
    }
}

struct EW { int jv[4]; float qv[4], dxv[4], dyv[4]; bool okv[4]; };

__device__ __forceinline__ void load_win(long e0, int beg, int end, int E,
        const int* __restrict__ ej, const float* __restrict__ qarr,
        const float2* __restrict__ dirs, EW& w) {
    if (e0 + 3 < (long)E) {
        int4   j4 = *(const int4*)(ej + e0);
        float4 q4 = *(const float4*)(qarr + e0);
        float4 dA = *(const float4*)((const float*)dirs + 2 * e0);
        float4 dB = *(const float4*)((const float*)dirs + 2 * e0 + 4);
        w.jv[0]=j4.x; w.jv[1]=j4.y; w.jv[2]=j4.z; w.jv[3]=j4.w;
        w.qv[0]=q4.x; w.qv[1]=q4.y; w.qv[2]=q4.z; w.qv[3]=q4.w;
        w.dxv[0]=dA.x; w.dyv[0]=dA.y; w.dxv[1]=dA.z; w.dyv[1]=dA.w;
        w.dxv[2]=dB.x; w.dyv[2]=dB.y; w.dxv[3]=dB.z; w.dyv[3]=dB.w;
    } else {
#pragma unroll
        for (int u = 0; u < 4; ++u) {
            long e = e0 + u;
            if (e < (long)E) {
                w.jv[u] = ej[e]; w.qv[u] = qarr[e];
                float2 d = dirs[e]; w.dxv[u] = d.x; w.dyv[u] = d.y;
            } else { w.jv[u]=0; w.qv[u]=0.f; w.dxv[u]=0.f; w.dyv[u]=0.f; }
        }
    }
#pragma unroll
    for (int u = 0; u < 4; ++u) {
        long e = e0 + u;
        w.okv[u] = (e >= (long)beg) && (e < (long)end);
    }
}

// ---------------------------------------------------------------------------
// Fused persistent kernel. phase<0: cooperative single launch with grid.sync.
// phase 0/1/2: fallback split (kernel boundaries provide sync).
//   P : rowptr + vd pack + zero tickets
//   AC: per-window M/A/B accumulate -> pinv -> gradRho -> g2/outp ; stream cst
//   D : out = K_OUT * (outp + sum_e <g2[j], c_e>)
// ---------------------------------------------------------------------------
__global__ __launch_bounds__(BLOCKT, 8)
void k_fused(const int* __restrict__ ei, const int* __restrict__ ej,
             const float* __restrict__ qarr, const float2* __restrict__ dirs,
             const float* __restrict__ vol, const float* __restrict__ dens,
             int* __restrict__ rowptr, float2* __restrict__ vd,
             __half2* __restrict__ cst, float2* __restrict__ g2,
             float* __restrict__ outp, float* __restrict__ out,
             int* __restrict__ tickets, int N, int E, int nwin, int phase) {
    __shared__ int    rp[NPB + 1];
    __shared__ float  acc6[NPB * 6];     // m00,m01,m11,A,Bx,By
    __shared__ float  Lild[NPB * 3];
    __shared__ float  gld[NPB * 2];
    __shared__ float  outl[NPB];
    __shared__ float2 vdl[NPB];
    __shared__ int    wsh;
    const int tid = threadIdx.x;

    // ---------------- phase P ----------------
    if (phase <= 0) {
        for (long e = (long)blockIdx.x * BLOCKT + tid; e <= (long)E;
             e += (long)gridDim.x * BLOCKT) {
            int prev = (e == 0)       ? -1 : ei[e - 1];
            int cur  = (e == (long)E) ? N  : ei[e];
            for (int t = prev + 1; t <= cur; ++t) rowptr[t] = (int)e;
        }
        for (long n = (long)blockIdx.x * BLOCKT + tid; n < (long)N;
             n += (long)gridDim.x * BLOCKT)
            vd[n] = make_float2(vol[n], dens[n]);
        if (blockIdx.x == 0 && tid < 2) tickets[tid] = 0;
    }
    if (phase < 0) cg::this_grid().sync();

    // ---------------- phase AC ----------------
    if (phase < 0 || phase == 1) {
        int   li_s[4 * SMAX];
        float gwx_s[4 * SMAX], gwy_s[4 * SMAX], val_s[4 * SMAX];
        for (;;) {
            if (tid == 0) wsh = atomicAdd(&tickets[0], 1);
            __syncthreads();
            const int w = wsh;
            if (w >= nwin) break;

            const int n0  = w * NPB;
            const int nHi = min(n0 + NPB, N);
            if (tid <= NPB) rp[tid] = rowptr[min(n0 + tid, nHi)];
            if (tid < NPB && n0 + tid < N) vdl[tid] = vd[n0 + tid];
            if (tid < NPB * 6) acc6[tid] = 0.f;
            if (tid < NPB * 2) gld[tid] = 0.f;
            __syncthreads();
            const int  beg = rp[0], end = rp[NPB];
            const long beg4 = (long)beg & ~3L;
            const int  waveBase = tid & ~(WAVE - 1);

#pragma unroll
            for (int x = 0; x < 4 * SMAX; ++x) { li_s[x] = -1; gwx_s[x]=gwy_s[x]=val_s[x]=0.f; }

            // ---- A: accumulate M(3)+A(1)+B(2), stream c_e ----
#pragma unroll
            for (int c = 0; c < SMAX; ++c) {
                long ebw = beg4 + ((long)c * BLOCKT + waveBase) * 4;
                if (ebw < (long)end) {
                    long e0 = beg4 + ((long)c * BLOCKT + tid) * 4;
                    EW wd; load_win(e0, beg, end, E, ej, qarr, dirs, wd);
                    const bool all4 = wd.okv[0] && wd.okv[1] && wd.okv[2] && wd.okv[3];
                    float4 cpack;
                    int k[4]; float v[4][6];
#pragma unroll
                    for (int u = 0; u < 4; ++u) {
                        k[u] = -1;
#pragma unroll
                        for (int c2 = 0; c2 < 6; ++c2) v[u][c2] = 0.f;
                        if (wd.okv[u]) {
                            int li = li_search(rp, (int)(e0 + u));
                            float q = wd.qv[u], dx = wd.dxv[u], dy = wd.dyv[u];
                            float2 vdj = vd[wd.jv[u]];
                            float wq = wendland_dkdq(q);
                            float s = -2.f * vdj.x * q * wq * INV_H2;   // >= 0
                            float w2 = wq * INV_H3;
                            float gwx = dx * w2, gwy = dy * w2;
                            float rx = -dx * q * H, ry = -dy * q * H;
                            float rji2 = rx * rx + ry * ry + EPS_REF;
                            float gT = (gwx * rx + gwy * ry) / rji2;
                            float gv = gT * vdj.x;
                            float rho_ba = REST_RHO * (vdj.y - vdl[li].y);
                            k[u] = li;
                            v[u][0] = s * dx * dx; v[u][1] = s * dx * dy; v[u][2] = s * dy * dy;
                            v[u][3] = rho_ba * gv; v[u][4] = rx * gv;    v[u][5] = ry * gv;
                            __half2 cp = __floats2half2_rn(0.5f * rx * gv, 0.5f * ry * gv);
                            if (all4) (&cpack.x)[u] = h2_as_f(cp);
                            else      cst[e0 + u] = cp;
                            li_s[c*4+u] = li; gwx_s[c*4+u] = gwx; gwy_s[c*4+u] = gwy;
                            val_s[c*4+u] = 2.f * rho_ba * vdj.x;
                        }
                    }
                    if (all4) ((float4*)cst)[e0 >> 2] = cpack;
                    seg_atomic4<6>(k, v, acc6);
                }
            }
            // overflow (window > SMAX*1024 edges; practically never at degree ~32)
            for (int c = SMAX; ; ++c) {
                long ebw = beg4 + ((long)c * BLOCKT + waveBase) * 4;
                if (ebw >= (long)end) break;
                long e0 = beg4 + ((long)c * BLOCKT + tid) * 4;
                EW wd; load_win(e0, beg, end, E, ej, qarr, dirs, wd);
                int k[4]; float v[4][6];
#pragma unroll
                for (int u = 0; u < 4; ++u) {
                    k[u] = -1;
#pragma unroll
                    for (int c2 = 0; c2 < 6; ++c2) v[u][c2] = 0.f;
                    if (wd.okv[u]) {
                        int li = li_search(rp, (int)(e0 + u));
                        float q = wd.qv[u], dx = wd.dxv[u], dy = wd.dyv[u];
                        float2 vdj = vd[wd.jv[u]];
                        float wq = wendland_dkdq(q);
                        float s = -2.f * vdj.x * q * wq * INV_H2;
                        float w2 = wq * INV_H3;
                        float gwx = dx * w2, gwy = dy * w2;
                        float rx = -dx * q * H, ry = -dy * q * H;
                        float rji2 = rx * rx + ry * ry + EPS_REF;
                        float gT = (gwx * rx + gwy * ry) / rji2;
                        float gv = gT * vdj.x;
                        float rho_ba = REST_RHO * (vdj.y - vdl[li].y);
                        k[u] = li;
                        v[u][0] = s * dx * dx; v[u][1] = s * dx * dy; v[u][2] = s * dy * dy;
                        v[u][3] = rho_ba * gv; v[u][4] = rx * gv;    v[u][5] = ry * gv;
                        cst[e0 + u] = __floats2half2_rn(0.5f * rx * gv, 0.5f * ry * gv);
                    }
                }
                seg_atomic4<6>(k, v, acc6);
            }
            __syncthreads();

            // ---- pinv (one lane per node), JAX cutoff semantics ----
            if (tid < NPB) {
                float a = acc6[6*tid], b = acc6[6*tid+1], cc = acc6[6*tid+2];
                float half_tr   = 0.5f * (a + cc);
                float half_diff = 0.5f * (a - cc);
                float disc = sqrtf(half_diff * half_diff + b * b);
                float l1 = half_tr + disc, l2 = half_tr - disc;
                float smax = fmaxf(fabsf(l1), fabsf(l2));
                float cutoff = 2.3841858e-6f * smax;   // rcond = 10*max(2,2)*eps_f32
                float i00 = 0.f, i01 = 0.f, i11 = 0.f;
                if (fabsf(l2) > cutoff) {
                    float inv = 1.0f / (a * cc - b * b);
                    i00 =  cc * inv; i01 = -b * inv; i11 = a * inv;
                } else if (fabsf(l1) > cutoff) {
                    float vax = b,       vay = l1 - a;
                    float vbx = l1 - cc, vby = b;
                    float na = vax*vax + vay*vay, nb = vbx*vbx + vby*vby;
                    float vx, vy, n2;
                    if (nb >= na) { vx = vbx; vy = vby; n2 = nb; }
                    else          { vx = vax; vy = vay; n2 = na; }
                    float inv = 1.0f / (l1 * n2);
                    i00 = vx*vx*inv; i01 = vx*vy*inv; i11 = vy*vy*inv;
                }
                Lild[3*tid] = i00; Lild[3*tid+1] = i01; Lild[3*tid+2] = i11;
            }
            __syncthreads();

            // ---- C: gradRho from stash ----
#pragma unroll
            for (int c = 0; c < SMAX; ++c) {
                long ebw = beg4 + ((long)c * BLOCKT + waveBase) * 4;
                if (ebw < (long)end) {
                    int k[4]; float v[4][2];
#pragma unroll
                    for (int u = 0; u < 4; ++u) {
                        int li = li_s[c*4+u];
                        k[u] = li; v[u][0] = v[u][1] = 0.f;
                        if (li >= 0) {
                            float gwx = gwx_s[c*4+u], gwy = gwy_s[c*4+u];
                            float L0 = Lild[3*li], L1 = Lild[3*li+1], L2v = Lild[3*li+2];
                            float gx = L0 * gwx + L1 * gwy;
                            float gy = L1 * gwx + L2v * gwy;
                            float dm = fabsf(gwx) + fabsf(gwy);
                            float nm = fabsf(gx) + fabsf(gy);
                            float change = fabsf(nm - dm) / (dm + 1e-4f * H);
                            if (!(change < 0.1f)) { gx = gwx; gy = gwy; }   // NaN -> fallback
                            v[u][0] = val_s[c*4+u] * gx;
                            v[u][1] = val_s[c*4+u] * gy;
                        }
                    }
                    seg_atomic4<2>(k, v, gld);
                }
            }
            for (int c = SMAX; ; ++c) {   // overflow recompute (rare)
                long ebw = beg4 + ((long)c * BLOCKT + waveBase) * 4;
                if (ebw >= (long)end) break;
                long e0 = beg4 + ((long)c * BLOCKT + tid) * 4;
                EW wd; load_win(e0, beg, end, E, ej, qarr, dirs, wd);
                int k[4]; float v[4][2];
#pragma unroll
                for (int u = 0; u < 4; ++u) {
                    k[u] = -1; v[u][0] = v[u][1] = 0.f;
                    if (wd.okv[u]) {
                        int li = li_search(rp, (int)(e0 + u));
                        float q = wd.qv[u], dx = wd.dxv[u], dy = wd.dyv[u];
                        float2 vdj = vd[wd.jv[u]];
                        float w2 = wendland_dkdq(q) * INV_H3;
                        float gwx = dx * w2, gwy = dy * w2;
                        float L0 = Lild[3*li], L1 = Lild[3*li+1], L2v = Lild[3*li+2];
                        float gx = L0 * gwx + L1 * gwy;
                        float gy = L1 * gwx + L2v * gwy;
                        float dm = fabsf(gwx) + fabsf(gwy);
                        float nm = fabsf(gx) + fabsf(gy);
                        float change = fabsf(nm - dm) / (dm + 1e-4f * H);
                        if (!(change < 0.1f)) { gx = gwx; gy = gwy; }
                        float val = 2.f * REST_RHO * (vdj.y - vdl[li].y) * vdj.x;
                        k[u] = li; v[u][0] = val * gx; v[u][1] = val * gy;
                    }
                }
                seg_atomic4<2>(k, v, gld);
            }
            __syncthreads();
            if (tid < NPB && n0 + tid < N) {
                float gx = gld[2*tid], gy = gld[2*tid+1];
                g2[n0 + tid]   = make_float2(gx, gy);
                outp[n0 + tid] = acc6[6*tid+3] + 0.5f * (gx * acc6[6*tid+4] + gy * acc6[6*tid+5]);
            }
        }
    }
    if (phase < 0) cg::this_grid().sync();

    // ---------------- phase D ----------------
    if (phase < 0 || phase == 2) {
        for (;;) {
            if (tid == 0) wsh = atomicAdd(&tickets[1], 1);
            __syncthreads();
            const int w = wsh;
            if (w >= nwin) break;

            const int n0  = w * NPB;
            const int nHi = min(n0 + NPB, N);
            if (tid < NPB) outl[tid] = 0.f;
            __syncthreads();
            const int  beg = rowptr[n0], end = rowptr[nHi];
            const long beg4 = (long)beg & ~3L;
            const int  waveBase = tid & ~(WAVE - 1);

            for (int c = 0; ; ++c) {
                long ebw = beg4 + ((long)c * BLOCKT + waveBase) * 4;
                if (ebw >= (long)end) break;
                long e0 = beg4 + ((long)c * BLOCKT + tid) * 4;
                int iv[4], jv[4]; float cv[4]; bool okv[4];
                if (e0 + 3 < (long)E) {
                    int4   i4 = *(const int4*)(ei + e0);
                    int4   j4 = *(const int4*)(ej + e0);
                    float4 c4 = ((const float4*)cst)[e0 >> 2];
                    iv[0]=i4.x; iv[1]=i4.y; iv[2]=i4.z; iv[3]=i4.w;
                    jv[0]=j4.x; jv[1]=j4.y; jv[2]=j4.z; jv[3]=j4.w;
                    cv[0]=c4.x; cv[1]=c4.y; cv[2]=c4.z; cv[3]=c4.w;
                } else {
#pragma unroll
                    for (int u = 0; u < 4; ++u) {
                        long e = e0 + u;
                        if (e < (long)E) { iv[u] = ei[e]; jv[u] = ej[e]; cv[u] = h2_as_f(cst[e]); }
                        else             { iv[u] = 0;     jv[u] = 0;     cv[u] = 0.f; }
                    }
                }
#pragma unroll
                for (int u = 0; u < 4; ++u) {
                    long e = e0 + u;
                    okv[u] = (e >= (long)beg) && (e < (long)end);
                }
                int k[4]; float v[4][1];
#pragma unroll
                for (int u = 0; u < 4; ++u) {
                    k[u] = -1; v[u][0] = 0.f;
                    if (okv[u]) {
                        float2 gj = g2[jv[u]];                 // L2/L3-resident gather
                        __half2 ch = f_as_h2(cv[u]);
                        k[u] = iv[u] - n0;                     // direct key
                        v[u][0] = gj.x * __low2float(ch) + gj.y * __high2float(ch);
                    }
                }
                seg_atomic4<1>(k, v, outl);
            }
            __syncthreads();
            if (tid < NPB && n0 + tid < N)
                out[n0 + tid] = K_OUT * (outp[n0 + tid] + outl[tid]);
        }
    }
}

extern "C" void kernel_launch(void* const* d_in, const int* in_sizes, int n_in,
                              void* d_out, int out_size, void* d_ws, size_t ws_size,
                              hipStream_t stream) {
    const float*  vol  = (const float*)d_in[1];
    const float*  dens = (const float*)d_in[2];
    const float2* dirs = (const float2*)d_in[3];
    const float*  qarr = (const float*)d_in[4];
    const int*    ei   = (const int*)d_in[5];
    const int*    ej   = (const int*)d_in[6];
    const int N = in_sizes[1];
    const int E = in_sizes[4];
    const int nwin = (N + NPB - 1) / NPB;

    // ws: rowptr int[N+1] | vd f2[N] | g2 f2[N] | outp f[N] | cst h2[E] | tickets int[2]
    size_t off = 0;
    auto alloc = [&](size_t bytes) { void* r = (char*)d_ws + off;
                                     off = (off + bytes + 15) & ~(size_t)15; return r; };
    int*     rowptr  = (int*)    alloc((size_t)(N + 1) * 4);
    float2*  vd      = (float2*) alloc((size_t)N * 8);
    float2*  g2      = (float2*) alloc((size_t)N * 8);
    float*   outp    = (float*)  alloc((size_t)N * 4);
    __half2* cst     = (__half2*)alloc((size_t)E * 4);
    int*     tickets = (int*)    alloc(2 * sizeof(int));
    float*   out     = (float*)d_out;

    // grid = max co-resident blocks (cached occupancy query; host-only, capture-safe)
    static int g_grid = 0;
    if (g_grid == 0) {
        int dev = 0; (void)hipGetDevice(&dev);
        hipDeviceProp_t prop;
        int cus = 256;
        if (hipGetDeviceProperties(&prop, dev) == hipSuccess) cus = prop.multiProcessorCount;
        int nb = 0;
        if (hipOccupancyMaxActiveBlocksPerMultiprocessor(&nb, k_fused, BLOCKT, 0) != hipSuccess || nb < 1)
            nb = 4;
        g_grid = nb * cus;
    }

    int phase = -1;
    void* args[] = { (void*)&ei, (void*)&ej, (void*)&qarr, (void*)&dirs,
                     (void*)&vol, (void*)&dens, (void*)&rowptr, (void*)&vd,
                     (void*)&cst, (void*)&g2, (void*)&outp, (void*)&out,
                     (void*)&tickets, (void*)&N, (void*)&E, (void*)&nwin, (void*)&phase };
    hipError_t rc = hipLaunchCooperativeKernel((void*)k_fused, dim3(g_grid), dim3(BLOCKT),
                                               args, 0, stream);
    if (rc != hipSuccess) {
        (void)hipGetLastError();   // clear; fall back to 3 ordered launches
        k_fused<<<g_grid, BLOCKT, 0, stream>>>(ei, ej, qarr, dirs, vol, dens, rowptr, vd,
                                               cst, g2, outp, out, tickets, N, E, nwin, 0);
        k_fused<<<g_grid, BLOCKT, 0, stream>>>(ei, ej, qarr, dirs, vol, dens, rowptr, vd,
                                               cst, g2, outp, out, tickets, N, E, nwin, 1);
        k_fused<<<g_grid, BLOCKT, 0, stream>>>(ei, ej, qarr, dirs, vol, dens, rowptr, vd,
                                               cst, g2, outp, out, tickets, N, E, nwin, 2);
    }
}

// Round 3
// 302.450 us; speedup vs baseline: 2.5783x; 2.5783x over previous
//
#include <hip/hip_runtime.h>
#include <hip/hip_fp16.h>
#include <math.h>

#define WAVE   64
#define NPB    32          // nodes per block
#define BLOCKT 256
#define SMAX   2           // stashed 1024-edge chunks (covers <=2048 edges/window)

// ---- constants from the reference ----
#define KC        2.2281692032865347f   // 7/pi
#define H         0.05f
#define INV_H2    400.0f
#define INV_H3    8000.0f
#define EPS_REF   0.00025f              // h^2 * 0.1
#define K_OUT     0.24261080f           // 2*h*DELTA*C0
#define REST_RHO  1000.0f

__device__ __forceinline__ float wendland_dkdq(float q) {
    float o = 1.f - q;
    return -20.f * q * o * o * o * KC;
}

union H2F { __half2 h; float f; };
__device__ __forceinline__ float   h2_as_f(__half2 h) { H2F u; u.h = h; return u.f; }
__device__ __forceinline__ __half2 f_as_h2(float f)   { H2F u; u.f = f; return u.h; }

// largest li in [0,NPB) with rp[li] <= e   (rp[0] <= e < rp[NPB] guaranteed)
__device__ __forceinline__ int li_search(const int* rp, int e) {
    int lo = 0;
#pragma unroll
    for (int s = NPB / 2; s >= 1; s >>= 1) lo += (rp[lo + s] <= e) ? s : 0;
    return lo;
}

// ---------------------------------------------------------------------------
// 4-edge-per-lane segmented accumulate via LDS float atomics (ds_add_f32).
// Equal keys contiguous in lane order; key<0 skipped (only at run ends).
// Replaces the 5-step shuffle scan: no serial cross-lane chain, ~24 fewer
// VGPRs of scan temps. Contention <= ~8-way (degree ~32 spans 8 lanes).
// ---------------------------------------------------------------------------
template<int NV>
__device__ __forceinline__ void seg_atomic4(const int k[4], float v[4][NV], float* base) {
    const bool s01 = (k[1] == k[0]);
    const bool s12 = (k[2] == k[1]);
    const bool s23 = (k[3] == k[2]);
    if (k[0] >= 0) {
        float s[NV];
#pragma unroll
        for (int c = 0; c < NV; ++c) {
            float t = v[0][c];
            if (s01)               t += v[1][c];
            if (s01 && s12)        t += v[2][c];
            if (s01 && s12 && s23) t += v[3][c];
            s[c] = t;
        }
#pragma unroll
        for (int c = 0; c < NV; ++c) atomicAdd(base + k[0] * NV + c, s[c]);
    }
    if (k[1] >= 0 && !s01) {
        float s[NV];
#pragma unroll
        for (int c = 0; c < NV; ++c) {
            float t = v[1][c];
            if (s12)        t += v[2][c];
            if (s12 && s23) t += v[3][c];
            s[c] = t;
        }
#pragma unroll
        for (int c = 0; c < NV; ++c) atomicAdd(base + k[1] * NV + c, s[c]);
    }
    if (k[2] >= 0 && !s12) {
        float s[NV];
#pragma unroll
        for (int c = 0; c < NV; ++c) {
            float t = v[2][c];
            if (s23) t += v[3][c];
            s[c] = t;
        }
#pragma unroll
        for (int c = 0; c < NV; ++c) atomicAdd(base + k[2] * NV + c, s[c]);
    }
    if (k[3] >= 0 && !s23) {
#pragma unroll
        for (int c = 0; c < NV; ++c) atomicAdd(base + k[3] * NV + c, v[3][c]);
    }
}

struct EW { int jv[4]; float qv[4], dxv[4], dyv[4]; bool okv[4]; };

__device__ __forceinline__ void load_win(long e0, int beg, int end, int E,
        const int* __restrict__ ej, const float* __restrict__ qarr,
        const float2* __restrict__ dirs, EW& w) {
    if (e0 + 3 < (long)E) {
        int4   j4 = *(const int4*)(ej + e0);
        float4 q4 = *(const float4*)(qarr + e0);
        float4 dA = *(const float4*)((const float*)dirs + 2 * e0);
        float4 dB = *(const float4*)((const float*)dirs + 2 * e0 + 4);
        w.jv[0]=j4.x; w.jv[1]=j4.y; w.jv[2]=j4.z; w.jv[3]=j4.w;
        w.qv[0]=q4.x; w.qv[1]=q4.y; w.qv[2]=q4.z; w.qv[3]=q4.w;
        w.dxv[0]=dA.x; w.dyv[0]=dA.y; w.dxv[1]=dA.z; w.dyv[1]=dA.w;
        w.dxv[2]=dB.x; w.dyv[2]=dB.y; w.dxv[3]=dB.z; w.dyv[3]=dB.w;
    } else {
#pragma unroll
        for (int u = 0; u < 4; ++u) {
            long e = e0 + u;
            if (e < (long)E) {
                w.jv[u] = ej[e]; w.qv[u] = qarr[e];
                float2 d = dirs[e]; w.dxv[u] = d.x; w.dyv[u] = d.y;
            } else { w.jv[u]=0; w.qv[u]=0.f; w.dxv[u]=0.f; w.dyv[u]=0.f; }
        }
    }
#pragma unroll
    for (int u = 0; u < 4; ++u) {
        long e = e0 + u;
        w.okv[u] = (e >= (long)beg) && (e < (long)end);
    }
}

// rowptr[t] = first edge e with i[e] >= t (i sorted); also pack vd=(vol,dens).
__global__ void k_prep(const int* __restrict__ ei, const float* __restrict__ vol,
                       const float* __restrict__ dens, int* __restrict__ rowptr,
                       float2* __restrict__ vd, int N, int E) {
    int e = blockIdx.x * blockDim.x + threadIdx.x;
    if (e <= E) {
        int prev = (e == 0) ? -1 : ei[e - 1];
        int cur  = (e == E) ? N  : ei[e];
        for (int t = prev + 1; t <= cur; ++t) rowptr[t] = e;
    }
    if (e < N) vd[e] = make_float2(vol[e], dens[e]);
}

// Fused A+B+C+term1/2 of D:
//   phase A: M(3) + A(1) + B(2) via one 6-wide LDS atomic accumulate; stream c_e
//   pinv -> phase C (gradRho from stash) -> outp = A + 0.5*g·B ; write g2, outp.
__global__ __launch_bounds__(BLOCKT, 4)
void k_AC(const int* __restrict__ ej, const float* __restrict__ qarr,
          const float2* __restrict__ dirs, const float2* __restrict__ vd,
          const int* __restrict__ rowptr, __half2* __restrict__ cst,
          float2* __restrict__ g2, float* __restrict__ outp, int N, int E) {
    __shared__ int    rp[NPB + 1];
    __shared__ float  acc6[NPB * 6];     // m00,m01,m11,A,Bx,By
    __shared__ float  Lild[NPB * 3];
    __shared__ float  gld[NPB * 2];
    __shared__ float2 vdl[NPB];
    const int tid = threadIdx.x;
    const int n0  = blockIdx.x * NPB;
    const int nHi = min(n0 + NPB, N);
    if (tid <= NPB) rp[tid] = rowptr[min(n0 + tid, nHi)];
    if (tid < NPB && n0 + tid < N) vdl[tid] = vd[n0 + tid];
    if (tid < NPB * 6) acc6[tid] = 0.f;
    if (tid < NPB * 2) gld[tid] = 0.f;
    __syncthreads();
    const int  beg = rp[0], end = rp[NPB];
    const long beg4 = (long)beg & ~3L;
    const int  waveBase = tid & ~(WAVE - 1);

    int   li_s[4 * SMAX];
    float gwx_s[4 * SMAX], gwy_s[4 * SMAX], val_s[4 * SMAX];
#pragma unroll
    for (int x = 0; x < 4 * SMAX; ++x) { li_s[x] = -1; gwx_s[x]=gwy_s[x]=val_s[x]=0.f; }

    // ---- phase A ----
#pragma unroll
    for (int c = 0; c < SMAX; ++c) {
        long ebw = beg4 + ((long)c * BLOCKT + waveBase) * 4;
        if (ebw < (long)end) {
            long e0 = beg4 + ((long)c * BLOCKT + tid) * 4;
            EW wd; load_win(e0, beg, end, E, ej, qarr, dirs, wd);
            const bool all4 = wd.okv[0] && wd.okv[1] && wd.okv[2] && wd.okv[3];
            float4 cpack;
            int    li4[4];
            float2 vdj4[4];
            // (a) all 4 searches, (b) all 4 gathers in flight, (c) compute
#pragma unroll
            for (int u = 0; u < 4; ++u)
                li4[u] = wd.okv[u] ? li_search(rp, (int)(e0 + u)) : -1;
#pragma unroll
            for (int u = 0; u < 4; ++u)
                vdj4[u] = wd.okv[u] ? vd[wd.jv[u]] : make_float2(0.f, 0.f);
            int k[4]; float v[4][6];
#pragma unroll
            for (int u = 0; u < 4; ++u) {
                k[u] = -1;
#pragma unroll
                for (int c2 = 0; c2 < 6; ++c2) v[u][c2] = 0.f;
                if (wd.okv[u]) {
                    int li = li4[u];
                    float q = wd.qv[u], dx = wd.dxv[u], dy = wd.dyv[u];
                    float2 vdj = vdj4[u];
                    float wq = wendland_dkdq(q);
                    float s = -2.f * vdj.x * q * wq * INV_H2;   // >= 0
                    float w = wq * INV_H3;
                    float gwx = dx * w, gwy = dy * w;
                    float rx = -dx * q * H, ry = -dy * q * H;
                    float rji2 = rx * rx + ry * ry + EPS_REF;
                    float gT = (gwx * rx + gwy * ry) / rji2;
                    float gv = gT * vdj.x;
                    float rho_ba = REST_RHO * (vdj.y - vdl[li].y);
                    k[u] = li;
                    v[u][0] = s * dx * dx; v[u][1] = s * dx * dy; v[u][2] = s * dy * dy;
                    v[u][3] = rho_ba * gv; v[u][4] = rx * gv;    v[u][5] = ry * gv;
                    __half2 cp = __floats2half2_rn(0.5f * rx * gv, 0.5f * ry * gv);
                    if (all4) (&cpack.x)[u] = h2_as_f(cp);
                    else      cst[e0 + u] = cp;
                    li_s[c*4+u] = li; gwx_s[c*4+u] = gwx; gwy_s[c*4+u] = gwy;
                    val_s[c*4+u] = 2.f * rho_ba * vdj.x;
                }
            }
            if (all4) ((float4*)cst)[e0 >> 2] = cpack;
            seg_atomic4<6>(k, v, acc6);
        }
    }
    // overflow (window > SMAX*1024 edges; practically never at avg degree 32)
    for (int c = SMAX; ; ++c) {
        long ebw = beg4 + ((long)c * BLOCKT + waveBase) * 4;
        if (ebw >= (long)end) break;
        long e0 = beg4 + ((long)c * BLOCKT + tid) * 4;
        EW wd; load_win(e0, beg, end, E, ej, qarr, dirs, wd);
        int k[4]; float v[4][6];
#pragma unroll
        for (int u = 0; u < 4; ++u) {
            k[u] = -1;
#pragma unroll
            for (int c2 = 0; c2 < 6; ++c2) v[u][c2] = 0.f;
            if (wd.okv[u]) {
                int li = li_search(rp, (int)(e0 + u));
                float q = wd.qv[u], dx = wd.dxv[u], dy = wd.dyv[u];
                float2 vdj = vd[wd.jv[u]];
                float wq = wendland_dkdq(q);
                float s = -2.f * vdj.x * q * wq * INV_H2;
                float w = wq * INV_H3;
                float gwx = dx * w, gwy = dy * w;
                float rx = -dx * q * H, ry = -dy * q * H;
                float rji2 = rx * rx + ry * ry + EPS_REF;
                float gT = (gwx * rx + gwy * ry) / rji2;
                float gv = gT * vdj.x;
                float rho_ba = REST_RHO * (vdj.y - vdl[li].y);
                k[u] = li;
                v[u][0] = s * dx * dx; v[u][1] = s * dx * dy; v[u][2] = s * dy * dy;
                v[u][3] = rho_ba * gv; v[u][4] = rx * gv;    v[u][5] = ry * gv;
                cst[e0 + u] = __floats2half2_rn(0.5f * rx * gv, 0.5f * ry * gv);
            }
        }
        seg_atomic4<6>(k, v, acc6);
    }
    __syncthreads();

    // ---- pinv (one lane per node), JAX cutoff semantics ----
    if (tid < NPB) {
        float a = acc6[6*tid], b = acc6[6*tid+1], cc = acc6[6*tid+2];
        float half_tr   = 0.5f * (a + cc);
        float half_diff = 0.5f * (a - cc);
        float disc = sqrtf(half_diff * half_diff + b * b);
        float l1 = half_tr + disc, l2 = half_tr - disc;
        float smax = fmaxf(fabsf(l1), fabsf(l2));
        float cutoff = 2.3841858e-6f * smax;   // rcond = 10*max(2,2)*eps_f32
        float i00 = 0.f, i01 = 0.f, i11 = 0.f;
        if (fabsf(l2) > cutoff) {
            float inv = 1.0f / (a * cc - b * b);
            i00 =  cc * inv; i01 = -b * inv; i11 = a * inv;
        } else if (fabsf(l1) > cutoff) {
            float vax = b,       vay = l1 - a;
            float vbx = l1 - cc, vby = b;
            float na = vax*vax + vay*vay, nb = vbx*vbx + vby*vby;
            float vx, vy, n2;
            if (nb >= na) { vx = vbx; vy = vby; n2 = nb; }
            else          { vx = vax; vy = vay; n2 = na; }
            float inv = 1.0f / (l1 * n2);
            i00 = vx*vx*inv; i01 = vx*vy*inv; i11 = vy*vy*inv;
        }
        Lild[3*tid] = i00; Lild[3*tid+1] = i01; Lild[3*tid+2] = i11;
    }
    __syncthreads();

    // ---- phase C: gradRho from stash ----
#pragma unroll
    for (int c = 0; c < SMAX; ++c) {
        long ebw = beg4 + ((long)c * BLOCKT + waveBase) * 4;
        if (ebw < (long)end) {
            int k[4]; float v[4][2];
#pragma unroll
            for (int u = 0; u < 4; ++u) {
                int li = li_s[c*4+u];
                k[u] = li; v[u][0] = v[u][1] = 0.f;
                if (li >= 0) {
                    float gwx = gwx_s[c*4+u], gwy = gwy_s[c*4+u];
                    float L0 = Lild[3*li], L1 = Lild[3*li+1], L2v = Lild[3*li+2];
                    float gx = L0 * gwx + L1 * gwy;
                    float gy = L1 * gwx + L2v * gwy;
                    float dm = fabsf(gwx) + fabsf(gwy);
                    float nm = fabsf(gx) + fabsf(gy);
                    float change = fabsf(nm - dm) / (dm + 1e-4f * H);
                    if (!(change < 0.1f)) { gx = gwx; gy = gwy; }   // NaN -> fallback
                    v[u][0] = val_s[c*4+u] * gx;
                    v[u][1] = val_s[c*4+u] * gy;
                }
            }
            seg_atomic4<2>(k, v, gld);
        }
    }
    for (int c = SMAX; ; ++c) {   // overflow recompute (rare)
        long ebw = beg4 + ((long)c * BLOCKT + waveBase) * 4;
        if (ebw >= (long)end) break;
        long e0 = beg4 + ((long)c * BLOCKT + tid) * 4;
        EW wd; load_win(e0, beg, end, E, ej, qarr, dirs, wd);
        int k[4]; float v[4][2];
#pragma unroll
        for (int u = 0; u < 4; ++u) {
            k[u] = -1; v[u][0] = v[u][1] = 0.f;
            if (wd.okv[u]) {
                int li = li_search(rp, (int)(e0 + u));
                float q = wd.qv[u], dx = wd.dxv[u], dy = wd.dyv[u];
                float2 vdj = vd[wd.jv[u]];
                float w = wendland_dkdq(q) * INV_H3;
                float gwx = dx * w, gwy = dy * w;
                float L0 = Lild[3*li], L1 = Lild[3*li+1], L2v = Lild[3*li+2];
                float gx = L0 * gwx + L1 * gwy;
                float gy = L1 * gwx + L2v * gwy;
                float dm = fabsf(gwx) + fabsf(gwy);
                float nm = fabsf(gx) + fabsf(gy);
                float change = fabsf(nm - dm) / (dm + 1e-4f * H);
                if (!(change < 0.1f)) { gx = gwx; gy = gwy; }
                float val = 2.f * REST_RHO * (vdj.y - vdl[li].y) * vdj.x;
                k[u] = li; v[u][0] = val * gx; v[u][1] = val * gy;
            }
        }
        seg_atomic4<2>(k, v, gld);
    }
    __syncthreads();
    if (tid < NPB && n0 + tid < N) {
        float gx = gld[2*tid], gy = gld[2*tid+1];
        g2[n0 + tid]   = make_float2(gx, gy);
        outp[n0 + tid] = acc6[6*tid+3] + 0.5f * (gx * acc6[6*tid+4] + gy * acc6[6*tid+5]);
    }
}

// Pass D (term 3 only): out = K_OUT * (outp + sum_e <g[j], c_e>).
__global__ __launch_bounds__(BLOCKT, 4)
void k_D(const int* __restrict__ ei, const int* __restrict__ ej,
         const __half2* __restrict__ cst,
         const float2* __restrict__ g2, const float* __restrict__ outp,
         const int* __restrict__ rowptr, float* __restrict__ out, int N, int E) {
    __shared__ float outl[NPB];
    const int tid = threadIdx.x;
    const int n0  = blockIdx.x * NPB;
    const int nHi = min(n0 + NPB, N);
    if (tid < NPB) outl[tid] = 0.f;
    __syncthreads();
    const int  beg = rowptr[n0], end = rowptr[nHi];
    const long beg4 = (long)beg & ~3L;
    const int  waveBase = tid & ~(WAVE - 1);

    for (int c = 0; ; ++c) {
        long ebw = beg4 + ((long)c * BLOCKT + waveBase) * 4;
        if (ebw >= (long)end) break;
        long e0 = beg4 + ((long)c * BLOCKT + tid) * 4;
        int iv[4], jv[4]; float cv[4]; bool okv[4];
        if (e0 + 3 < (long)E) {
            int4   i4 = *(const int4*)(ei + e0);
            int4   j4 = *(const int4*)(ej + e0);
            float4 c4 = ((const float4*)cst)[e0 >> 2];
            iv[0]=i4.x; iv[1]=i4.y; iv[2]=i4.z; iv[3]=i4.w;
            jv[0]=j4.x; jv[1]=j4.y; jv[2]=j4.z; jv[3]=j4.w;
            cv[0]=c4.x; cv[1]=c4.y; cv[2]=c4.z; cv[3]=c4.w;
        } else {
#pragma unroll
            for (int u = 0; u < 4; ++u) {
                long e = e0 + u;
                if (e < (long)E) { iv[u] = ei[e]; jv[u] = ej[e]; cv[u] = h2_as_f(cst[e]); }
                else             { iv[u] = 0;     jv[u] = 0;     cv[u] = 0.f; }
            }
        }
#pragma unroll
        for (int u = 0; u < 4; ++u) {
            long e = e0 + u;
            okv[u] = (e >= (long)beg) && (e < (long)end);
        }
        // all 4 gathers issued before use
        float2 gj4[4];
#pragma unroll
        for (int u = 0; u < 4; ++u)
            gj4[u] = okv[u] ? g2[jv[u]] : make_float2(0.f, 0.f);
        int k[4]; float v[4][1];
#pragma unroll
        for (int u = 0; u < 4; ++u) {
            k[u] = -1; v[u][0] = 0.f;
            if (okv[u]) {
                __half2 ch = f_as_h2(cv[u]);
                k[u] = iv[u] - n0;                     // direct key, no search
                v[u][0] = gj4[u].x * __low2float(ch) + gj4[u].y * __high2float(ch);
            }
        }
        seg_atomic4<1>(k, v, outl);
    }
    __syncthreads();
    if (tid < NPB && n0 + tid < N)
        out[n0 + tid] = K_OUT * (outp[n0 + tid] + outl[tid]);
}

extern "C" void kernel_launch(void* const* d_in, const int* in_sizes, int n_in,
                              void* d_out, int out_size, void* d_ws, size_t ws_size,
                              hipStream_t stream) {
    const float*  vol  = (const float*)d_in[1];
    const float*  dens = (const float*)d_in[2];
    const float2* dirs = (const float2*)d_in[3];
    const float*  qarr = (const float*)d_in[4];
    const int*    ei   = (const int*)d_in[5];
    const int*    ej   = (const int*)d_in[6];
    const int N = in_sizes[1];
    const int E = in_sizes[4];

    // ws: rowptr int[N+1] | vd f2[N] | g2 f2[N] | outp f[N] | cst h2[E]  (~30.5 MB)
    size_t off = 0;
    auto alloc = [&](size_t bytes) { void* r = (char*)d_ws + off;
                                     off = (off + bytes + 15) & ~(size_t)15; return r; };
    int*     rowptr = (int*)    alloc((size_t)(N + 1) * 4);
    float2*  vd     = (float2*) alloc((size_t)N * 8);
    float2*  g2     = (float2*) alloc((size_t)N * 8);
    float*   outp   = (float*)  alloc((size_t)N * 4);
    __half2* cst    = (__half2*)alloc((size_t)E * 4);
    float*   out    = (float*)d_out;

    const int tb = 256;
    const int gP = (E + 1 + tb - 1) / tb;
    const int gB = (N + NPB - 1) / NPB;

    k_prep<<<gP, tb, 0, stream>>>(ei, vol, dens, rowptr, vd, N, E);
    k_AC  <<<gB, BLOCKT, 0, stream>>>(ej, qarr, dirs, vd, rowptr, cst, g2, outp, N, E);
    k_D   <<<gB, BLOCKT, 0, stream>>>(ei, ej, cst, g2, outp, rowptr, out, N, E);
}